// Round 16
// baseline (2815.190 us; speedup 1.0000x reference)
//
#include <hip/hip_runtime.h>
#include <hip/hip_bf16.h>
#include <stdint.h>

#define B_ROWS 16384
#define DIM 2048
#define MAXPR 17152   // 67 * 256 max padded rows

typedef float f32x4 __attribute__((ext_vector_type(4)));
typedef short bf16x8 __attribute__((ext_vector_type(8)));
using u16 = unsigned short;
using u32 = unsigned int;

__device__ __forceinline__ u32 pack_bf2(float a, float b) {
  __hip_bfloat162 t = __float22bfloat162_rn(float2{a, b});
  union { __hip_bfloat162 b2; u32 u; } cv;
  cv.b2 = t;
  return cv.u;
}

__device__ __forceinline__ u16 f2bf_rne(float f) {
  union { float f; u32 u; } v;
  v.f = f;
  u32 u = v.u;
  u32 r = u + 0x7FFFu + ((u >> 16) & 1u);
  return (u16)(r >> 16);
}

__device__ __forceinline__ void gload16(const void* g, void* l) {
  __builtin_amdgcn_global_load_lds(
      (const __attribute__((address_space(1))) u32*)g,
      (__attribute__((address_space(3))) u32*)l, 16, 0, 0);
}

// ---- prep2: flags (fp64 last-col dot) + x->bf16 + h->bf16 (natural order) --
__global__ __launch_bounds__(256) void k_prep2(
    const float* __restrict__ x, const float* __restrict__ h,
    const float* __restrict__ W_ih, int* __restrict__ flags,
    u16* __restrict__ xb, u16* __restrict__ hb) {
  int row = blockIdx.x * 4 + (threadIdx.x >> 6);
  int lane = threadIdx.x & 63;
  const float* xr = x + (size_t)row * DIM;
  const float* hr = h + (size_t)row * DIM;
  const float* wr = W_ih + (size_t)(DIM - 1) * DIM;
  u16* xbr = xb + (size_t)row * DIM;
  u16* hbr = hb + (size_t)row * DIM;
  double s = 0.0;
#pragma unroll
  for (int i = 0; i < 8; ++i) {
    int idx = (i * 64 + lane) * 4;
    f32x4 xv = *(const f32x4*)(xr + idx);
    f32x4 wv = *(const f32x4*)(wr + idx);
    f32x4 hv = *(const f32x4*)(hr + idx);
    s += (double)xv.x * wv.x + (double)xv.y * wv.y +
         (double)xv.z * wv.z + (double)xv.w * wv.w;
    *(uint2*)(xbr + idx) = uint2{pack_bf2(xv.x, xv.y), pack_bf2(xv.z, xv.w)};
    *(uint2*)(hbr + idx) = uint2{pack_bf2(hv.x, hv.y), pack_bf2(hv.z, hv.w)};
  }
#pragma unroll
  for (int off = 32; off > 0; off >>= 1) s += __shfl_xor(s, off);
  if (lane == 0) {
    float hl = hr[DIM - 1];
    flags[row] = (s < -1.0) ? 2 : (hl > 0.f ? 0 : (hl < 0.f ? 1 : 3));
  }
}

// ---- scan: deterministic compaction order (single block, no atomics) -------
__global__ __launch_bounds__(256) void k_scan(const int* __restrict__ flags,
                                              int* __restrict__ iperm,
                                              int* __restrict__ meta) {
  __shared__ int sF[257], sI[257], sP[257];
  int t = threadIdx.x;
  int cF = 0, cI = 0, cP = 0;
  for (int i = 0; i < 64; ++i) {
    int f = flags[t * 64 + i];
    cF += (f == 0); cI += (f == 1); cP += (f >= 2);
  }
  sF[t + 1] = cF; sI[t + 1] = cI; sP[t + 1] = cP;
  for (int i = t; i < MAXPR; i += 256) iperm[i] = -1;
  __syncthreads();
  if (t == 0) {
    sF[0] = sI[0] = sP[0] = 0;
    for (int i = 1; i <= 256; ++i) {
      sF[i] += sF[i - 1]; sI[i] += sI[i - 1]; sP[i] += sP[i - 1];
    }
  }
  __syncthreads();
  int totF = sF[256], totI = sI[256], totP = sP[256];
  int padF = (totF + 255) & ~255;
  int padI = (totI + 255) & ~255;
  int rowsFI = padF + padI;
  int nrows = rowsFI + totP;
  if (t == 0) {
    meta[0] = (nrows + 255) >> 8;   // nrt
    meta[1] = rowsFI >> 8;          // tilesFI
    meta[2] = rowsFI;
    meta[3] = padF;
  }
  int oF = sF[t], oI = padF + sI[t], oP = rowsFI + sP[t];
  for (int i = 0; i < 64; ++i) {
    int r = t * 64 + i;
    int f = flags[r];
    if (f == 0) iperm[oF++] = r;
    else if (f == 1) iperm[oI++] = r;
    else iperm[oP++] = r;
  }
}

// ---- convert W_ih ([N][K] already) f32 -> bf16 ------------------------------
__global__ __launch_bounds__(256) void k_convert(const float* __restrict__ src,
                                                 u16* __restrict__ dst) {
  size_t i = ((size_t)blockIdx.x * 256 + threadIdx.x) * 4;
  f32x4 v = *(const f32x4*)(src + i);
  *(uint2*)(dst + i) = uint2{pack_bf2(v.x, v.y), pack_bf2(v.z, v.w)};
}

// ---- transpose+convert [K][N] f32 -> [N][K] bf16 ----------------------------
__global__ __launch_bounds__(256) void k_transpose(const float* __restrict__ src,
                                                   u16* __restrict__ dst) {
  __shared__ float tile[32][33];
  int k0 = blockIdx.x * 32;
  int n0 = blockIdx.y * 32;
  int tx = threadIdx.x & 31;
  int ty = threadIdx.x >> 5;
#pragma unroll
  for (int i = 0; i < 4; ++i)
    tile[ty + 8 * i][tx] = src[(size_t)(k0 + ty + 8 * i) * DIM + n0 + tx];
  __syncthreads();
#pragma unroll
  for (int i = 0; i < 4; ++i)
    dst[(size_t)(n0 + ty + 8 * i) * DIM + k0 + tx] = f2bf_rne(tile[tx][ty + 8 * i]);
}

// ---- 256^2 GEMM, virtual compaction + XCD bands, 2 blocks/CU ----------------
// Change vs R15: LDS shrinks 128KB -> 64KB (two 32KB slabs, one BK=32 K-half
// pair each) so TWO blocks co-reside per CU. Cross-block overlap (m97/m114
// mechanism: ~3 blocks/CU gave 874TF with per-step vmcnt(0) drains) covers
// each block's LDS-read window with the other block's MFMA cluster -- the
// overlap that 11 rounds of intra-block scheduling could not produce (per
// wave, reads issue after the prior MFMA issue window; first MFMA needs the
// 9th read -> LDS and MFMA windows serialize inside one barrier-locked
// block). Tile size/traffic/swizzle/gather/band-map identical to R15.
// Pipeline: stage slab (P+1)&1 at phase start; reads+MFMA on slab P&1;
// vmcnt(0) after MFMA (~1200cyc cover vs L2 ~300) + barrier.
__global__ __launch_bounds__(512, 4) void k_gemm8(
    const u16* __restrict__ xb, const u16* __restrict__ hb,
    const u16* __restrict__ Wih, const u16* __restrict__ WhhT,
    const u16* __restrict__ WinvT, const int* __restrict__ iperm,
    const int* __restrict__ flags, const int* __restrict__ meta,
    const float* __restrict__ h, float* __restrict__ out) {
  __shared__ __attribute__((aligned(128))) char smem[65536];

  int nrt = meta[0];
  int tilesFI = meta[1];
  int tilesF = meta[3] >> 8;

  int o = blockIdx.x;                    // 576 blocks
  int b = o & 7;                         // XCD band (round-robin dispatch)
  int q = o >> 3;                        // 0..71
  int rt = b + 8 * (q >> 3);             // rts interleaved mod 8 per XCD
  int bcol = (q & 7) * 256;
  int brow = rt * 256;
  if (rt >= nrt) return;
  const int NTb = (rt < tilesFI) ? 64 : 32;
  const int NPH = 2 * NTb;               // BK=32 phases
  const u16* Bh = (rt < tilesF) ? WhhT : WinvT;

  int t = threadIdx.x;
  int lane = t & 63;
  int wave = t >> 6;
  int wr = wave >> 2;                    // 0..1  (M half)
  int wc = wave & 3;                     // 0..3  (N quarter)

  // staging source-chunk swizzle: chunk = (lane&3) ^ ((lane>>3)&3)
  int sx16 = (((lane & 3) ^ ((lane >> 3) & 3)) << 4);
  // fragment read chunk swizzle: chunk = (lane>>4) ^ ((lane>>1)&3)
  int fA = (((lane >> 4) ^ ((lane >> 1) & 3)) << 4);
  int arowbase = wr * 128 + (lane & 15);
  int browbase = wc * 64 + (lane & 15);

  // per-job A-row gather: this thread's 2 staging rows, resolved once
  int pr0 = brow + wave * 32 + (lane >> 2);
  int rA0 = iperm[pr0];      if (rA0 < 0) rA0 = 0;
  int rA1 = iperm[pr0 + 16]; if (rA1 < 0) rA1 = 0;
  size_t aoff0 = (size_t)rA0 * (DIM * 2) + sx16;
  size_t aoff1 = (size_t)rA1 * (DIM * 2) + sx16;
  size_t boff = (size_t)(bcol + wave * 32 + (lane >> 2)) * (DIM * 2) + sx16;

  // stage one BK=32 slab pair (A 256x32 =16KB @0, B 256x32 =16KB @16384)
  auto stage = [&](int p) {
    if (p >= NPH) p -= NPH;
    int T = p >> 1;
    int kk = p & 1;
    int s = T >> 5;                      // 0: x-seg, 1: h-seg
    int kt = T & 31;
    size_t kb = (size_t)kt * 128 + (size_t)kk * 64;
    char* base = smem + (p & 1) * 32768 + (wave * 32) * 64;
    const char* Am = (const char*)(s ? hb : xb);
    const char* Bm = (const char*)(s ? Bh : Wih);
    gload16(Am + aoff0 + kb, base);
    gload16(Am + aoff1 + kb, base + 1024);
    gload16(Bm + boff + kb, base + 16384);
    gload16(Bm + boff + (size_t)16 * (DIM * 2) + kb, base + 16384 + 1024);
  };

  f32x4 acc[8][4] = {};
  bf16x8 aF[8], bF[4];

  // prologue: slab 0 staged and drained
  stage(0);
  asm volatile("s_waitcnt vmcnt(0)" ::: "memory");
  __builtin_amdgcn_s_barrier();
  asm volatile("" ::: "memory");

#pragma unroll 1
  for (int P = 0; P < NPH; ++P) {
    stage(P + 1);                        // issue early: ~1200cyc latency cover
    const char* Ab_ = smem + (P & 1) * 32768;
#pragma unroll
    for (int m = 0; m < 4; ++m) {
      aF[m] = *(const bf16x8*)(Ab_ + (arowbase + m * 16) * 64 + fA);
      aF[4 + m] = *(const bf16x8*)(Ab_ + (arowbase + 64 + m * 16) * 64 + fA);
    }
#pragma unroll
    for (int n = 0; n < 4; ++n)
      bF[n] = *(const bf16x8*)(Ab_ + 16384 + (browbase + n * 16) * 64 + fA);
    __builtin_amdgcn_s_setprio(1);
#pragma unroll
    for (int mh = 0; mh < 2; ++mh)
#pragma unroll
      for (int m = 0; m < 4; ++m)
#pragma unroll
        for (int n = 0; n < 4; ++n)
          acc[mh * 4 + m][n] = __builtin_amdgcn_mfma_f32_16x16x32_bf16(
              aF[mh * 4 + m], bF[n], acc[mh * 4 + m][n], 0, 0, 0);
    __builtin_amdgcn_s_setprio(0);
    asm volatile("s_waitcnt vmcnt(0)" ::: "memory");
    __builtin_amdgcn_s_barrier();
    asm volatile("" ::: "memory");
  }

  // epilogue: scatter rows via iperm; add h for flag==2 (pass) rows
#pragma unroll
  for (int mi = 0; mi < 8; ++mi) {
    int pbase = brow + wr * 128 + (mi >> 2) * 64 + (mi & 3) * 16 +
                (lane >> 4) * 4;
#pragma unroll
    for (int j = 0; j < 4; ++j) {
      int p = pbase + j;
      int orig = iperm[p];
      if (orig >= 0) {
        bool pass = (flags[orig] == 2);
#pragma unroll
        for (int n = 0; n < 4; ++n) {
          int col = bcol + wc * 64 + n * 16 + (lane & 15);
          float v = acc[mi][n][j];
          if (pass) v += h[(size_t)orig * DIM + col];
          out[(size_t)orig * DIM + col] = v;
        }
      }
    }
  }
}

// ---- fallback (ws too small): reg-staged 3-segment masked GEMM --------------
#define BM 128
#define BN 128
#define BK 64
__global__ __launch_bounds__(256, 2) void k_gemm_fb(
    const float* __restrict__ x, const float* __restrict__ h,
    const u16* __restrict__ Wih, const u16* __restrict__ WhhT,
    const u16* __restrict__ WinvT, const int* __restrict__ flags,
    float* __restrict__ out) {
  __shared__ char smem[(BM + BN) * BK * 2];
  char* sA = smem;
  char* sB = smem + BM * BK * 2;

  int o = blockIdx.x;
  int swz = (o & 7) * ((int)gridDim.x >> 3) + (o >> 3);
  int brow = (swz >> 4) * BM;
  int bcol = (swz & 15) * BN;

  int t = threadIdx.x;
  int lane = t & 63;
  int wave = t >> 6;
  int wrow = (wave >> 1) * 64;
  int wcol = (wave & 1) * 64;

  f32x4 acc[4][4] = {};
  int sc = t & 15;
  int sr0 = t >> 4;

  int aOff[4][2], bOff[4][2];
#pragma unroll
  for (int m = 0; m < 4; ++m)
#pragma unroll
    for (int kk = 0; kk < 2; ++kk) {
      int ar = wrow + m * 16 + (lane & 15);
      aOff[m][kk] = ar * (BK * 2) + ((kk * 64 + (lane >> 4) * 16) ^ ((ar & 7) << 4));
      int br = wcol + m * 16 + (lane & 15);
      bOff[m][kk] = br * (BK * 2) + ((kk * 64 + (lane >> 4) * 16) ^ ((br & 7) << 4));
    }

#pragma unroll 1
  for (int seg = 0; seg < 3; ++seg) {
    const float* Asrc = (seg == 0) ? x : h;
    const u16* Bsrc = (seg == 0) ? Wih : (seg == 1) ? WhhT : WinvT;
    int want = seg - 1;

    float rmask[8];
#pragma unroll
    for (int i = 0; i < 8; ++i) {
      int r = sr0 + 16 * i;
      rmask[i] = (want < 0 || flags[brow + r] == want) ? 1.f : 0.f;
    }

#pragma unroll 1
    for (int k0 = 0; k0 < DIM; k0 += BK) {
      __syncthreads();
#pragma unroll
      for (int i = 0; i < 8; ++i) {
        int r = sr0 + 16 * i;
        f32x4 v = *(const f32x4*)(Asrc + (size_t)(brow + r) * DIM + k0 + sc * 4);
        float msk = rmask[i];
        int off = r * (BK * 2) + ((sc * 8) ^ ((r & 7) << 4));
        *(uint2*)(sA + off) =
            uint2{pack_bf2(v.x * msk, v.y * msk), pack_bf2(v.z * msk, v.w * msk)};
      }
#pragma unroll
      for (int i = 0; i < 4; ++i) {
        int ch = t + 256 * i;
        int r = ch >> 3;
        int c = ch & 7;
        uint4 v = *(const uint4*)(Bsrc + (size_t)(bcol + r) * DIM + k0 + c * 8);
        int off = r * (BK * 2) + ((c * 16) ^ ((r & 7) << 4));
        *(uint4*)(sB + off) = v;
      }
      __syncthreads();
      bf16x8 aF2[4][2], bF2[4][2];
#pragma unroll
      for (int m = 0; m < 4; ++m)
#pragma unroll
        for (int kk = 0; kk < 2; ++kk) {
          aF2[m][kk] = *(const bf16x8*)(sA + aOff[m][kk]);
          bF2[m][kk] = *(const bf16x8*)(sB + bOff[m][kk]);
        }
#pragma unroll
      for (int kk = 0; kk < 2; ++kk)
#pragma unroll
        for (int m = 0; m < 4; ++m)
#pragma unroll
          for (int n = 0; n < 4; ++n)
            acc[m][n] = __builtin_amdgcn_mfma_f32_16x16x32_bf16(
                aF2[m][kk], bF2[n][kk], acc[m][n], 0, 0, 0);
    }
  }

#pragma unroll
  for (int m = 0; m < 4; ++m) {
    int rbase = brow + wrow + m * 16 + (lane >> 4) * 4;
#pragma unroll
    for (int j = 0; j < 4; ++j) {
      int row = rbase + j;
      bool pass = (flags[row] == 2);
#pragma unroll
      for (int n = 0; n < 4; ++n) {
        int col = bcol + wcol + n * 16 + (lane & 15);
        float v = acc[m][n][j];
        if (pass) v += h[(size_t)row * DIM + col];
        out[(size_t)row * DIM + col] = v;
      }
    }
  }
}

extern "C" void kernel_launch(void* const* d_in, const int* in_sizes, int n_in,
                              void* d_out, int out_size, void* d_ws, size_t ws_size,
                              hipStream_t stream) {
  const float* x = (const float*)d_in[0];
  const float* h = (const float*)d_in[1];
  const float* W_ih = (const float*)d_in[2];
  const float* W_hh = (const float*)d_in[3];
  const float* W_inv = (const float*)d_in[4];
  float* out = (float*)d_out;

  char* ws = (char*)d_ws;
  int* flags = (int*)ws;                                  // 64 KB
  int* meta = (int*)(ws + 65536);                         // 256 B
  int* iperm = (int*)(ws + 65536 + 256);                  // 67 KB
  u16* WihB = (u16*)(ws + 139264);                        // 8 MB
  u16* WhhT = WihB + (size_t)DIM * DIM;                   // 8 MB
  u16* WinvT = WhhT + (size_t)DIM * DIM;                  // 8 MB
  u16* xb = WinvT + (size_t)DIM * DIM;                    // 64 MB
  u16* hb = xb + (size_t)B_ROWS * DIM;                    // 64 MB
  size_t need = 139264 + 3ull * DIM * DIM * 2 + 2ull * B_ROWS * DIM * 2;

  k_convert<<<(DIM * DIM / 4) / 256, 256, 0, stream>>>(W_ih, WihB);
  k_transpose<<<dim3(DIM / 32, DIM / 32), 256, 0, stream>>>(W_hh, WhhT);
  k_transpose<<<dim3(DIM / 32, DIM / 32), 256, 0, stream>>>(W_inv, WinvT);

  if (ws_size >= need) {
    k_prep2<<<B_ROWS / 4, 256, 0, stream>>>(x, h, W_ih, flags, xb, hb);
    k_scan<<<1, 256, 0, stream>>>(flags, iperm, meta);
    k_gemm8<<<72 * 8, 512, 0, stream>>>(xb, hb, WihB, WhhT, WinvT, iperm,
                                        flags, meta, h, out);
  } else {
    k_prep2<<<B_ROWS / 4, 256, 0, stream>>>(x, h, W_ih, flags,
                                            (u16*)(ws + 139264),
                                            (u16*)(ws + 139264));
    k_gemm_fb<<<(B_ROWS / BM) * (DIM / BN), 256, 0, stream>>>(x, h, WihB, WhhT,
                                                              WinvT, flags, out);
  }
}

// Round 17
// 436.517 us; speedup vs baseline: 6.4492x; 6.4492x over previous
//
#include <hip/hip_runtime.h>
#include <hip/hip_bf16.h>
#include <stdint.h>

#define B_ROWS 16384
#define DIM 2048
#define BK 64
#define MAXPR 16896   // 132 * 128 max padded rows

typedef float f32x4 __attribute__((ext_vector_type(4)));
typedef short bf16x8 __attribute__((ext_vector_type(8)));
using u16 = unsigned short;
using u32 = unsigned int;

__device__ __forceinline__ u32 pack_bf2(float a, float b) {
  __hip_bfloat162 t = __float22bfloat162_rn(float2{a, b});
  union { __hip_bfloat162 b2; u32 u; } cv;
  cv.b2 = t;
  return cv.u;
}

__device__ __forceinline__ u16 f2bf_rne(float f) {
  union { float f; u32 u; } v;
  v.f = f;
  u32 u = v.u;
  u32 r = u + 0x7FFFu + ((u >> 16) & 1u);
  return (u16)(r >> 16);
}

__device__ __forceinline__ void gload16(const void* g, void* l) {
  __builtin_amdgcn_global_load_lds(
      (const __attribute__((address_space(1))) u32*)g,
      (__attribute__((address_space(3))) u32*)l, 16, 0, 0);
}

// ---- prep2: flags (fp64 last-col dot) + x->bf16 + h->bf16 (natural order) --
__global__ __launch_bounds__(256) void k_prep2(
    const float* __restrict__ x, const float* __restrict__ h,
    const float* __restrict__ W_ih, int* __restrict__ flags,
    u16* __restrict__ xb, u16* __restrict__ hb) {
  int row = blockIdx.x * 4 + (threadIdx.x >> 6);
  int lane = threadIdx.x & 63;
  const float* xr = x + (size_t)row * DIM;
  const float* hr = h + (size_t)row * DIM;
  const float* wr = W_ih + (size_t)(DIM - 1) * DIM;
  u16* xbr = xb + (size_t)row * DIM;
  u16* hbr = hb + (size_t)row * DIM;
  double s = 0.0;
#pragma unroll
  for (int i = 0; i < 8; ++i) {
    int idx = (i * 64 + lane) * 4;
    f32x4 xv = *(const f32x4*)(xr + idx);
    f32x4 wv = *(const f32x4*)(wr + idx);
    f32x4 hv = *(const f32x4*)(hr + idx);
    s += (double)xv.x * wv.x + (double)xv.y * wv.y +
         (double)xv.z * wv.z + (double)xv.w * wv.w;
    *(uint2*)(xbr + idx) = uint2{pack_bf2(xv.x, xv.y), pack_bf2(xv.z, xv.w)};
    *(uint2*)(hbr + idx) = uint2{pack_bf2(hv.x, hv.y), pack_bf2(hv.z, hv.w)};
  }
#pragma unroll
  for (int off = 32; off > 0; off >>= 1) s += __shfl_xor(s, off);
  if (lane == 0) {
    float hl = hr[DIM - 1];
    flags[row] = (s < -1.0) ? 2 : (hl > 0.f ? 0 : (hl < 0.f ? 1 : 3));
  }
}

// ---- scan: deterministic compaction order, 128-row granularity --------------
__global__ __launch_bounds__(256) void k_scan(const int* __restrict__ flags,
                                              int* __restrict__ iperm,
                                              int* __restrict__ meta) {
  __shared__ int sF[257], sI[257], sP[257];
  int t = threadIdx.x;
  int cF = 0, cI = 0, cP = 0;
  for (int i = 0; i < 64; ++i) {
    int f = flags[t * 64 + i];
    cF += (f == 0); cI += (f == 1); cP += (f >= 2);
  }
  sF[t + 1] = cF; sI[t + 1] = cI; sP[t + 1] = cP;
  for (int i = t; i < MAXPR; i += 256) iperm[i] = -1;
  __syncthreads();
  if (t == 0) {
    sF[0] = sI[0] = sP[0] = 0;
    for (int i = 1; i <= 256; ++i) {
      sF[i] += sF[i - 1]; sI[i] += sI[i - 1]; sP[i] += sP[i - 1];
    }
  }
  __syncthreads();
  int totF = sF[256], totI = sI[256], totP = sP[256];
  int padF = (totF + 127) & ~127;
  int padI = (totI + 127) & ~127;
  int rowsFI = padF + padI;
  int nrows = rowsFI + totP;
  if (t == 0) {
    meta[0] = (nrows + 127) >> 7;   // nrt (128-row tiles)
    meta[1] = rowsFI >> 7;          // tilesFI
    meta[2] = rowsFI;
    meta[3] = padF;
  }
  int oF = sF[t], oI = padF + sI[t], oP = rowsFI + sP[t];
  for (int i = 0; i < 64; ++i) {
    int r = t * 64 + i;
    int f = flags[r];
    if (f == 0) iperm[oF++] = r;
    else if (f == 1) iperm[oI++] = r;
    else iperm[oP++] = r;
  }
}

// ---- convert W_ih ([N][K] already) f32 -> bf16 ------------------------------
__global__ __launch_bounds__(256) void k_convert(const float* __restrict__ src,
                                                 u16* __restrict__ dst) {
  size_t i = ((size_t)blockIdx.x * 256 + threadIdx.x) * 4;
  f32x4 v = *(const f32x4*)(src + i);
  *(uint2*)(dst + i) = uint2{pack_bf2(v.x, v.y), pack_bf2(v.z, v.w)};
}

// ---- transpose+convert [K][N] f32 -> [N][K] bf16 ----------------------------
__global__ __launch_bounds__(256) void k_transpose(const float* __restrict__ src,
                                                   u16* __restrict__ dst) {
  __shared__ float tile[32][33];
  int k0 = blockIdx.x * 32;
  int n0 = blockIdx.y * 32;
  int tx = threadIdx.x & 31;
  int ty = threadIdx.x >> 5;
#pragma unroll
  for (int i = 0; i < 4; ++i)
    tile[ty + 8 * i][tx] = src[(size_t)(k0 + ty + 8 * i) * DIM + n0 + tx];
  __syncthreads();
#pragma unroll
  for (int i = 0; i < 4; ++i)
    dst[(size_t)(n0 + ty + 8 * i) * DIM + k0 + tx] = f2bf_rne(tile[tx][ty + 8 * i]);
}

// ---- compacted 128^2 GEMM: R2's proven m97-structure + virtual gather -------
// R2 body (493us full-work, 836TF, 2-3 blocks/CU cross-block overlap)
// bit-identical: 32KB single-buffered LDS, barrier-drained staging (compiler
// emits vmcnt(0) before s_barrier), proven swizzle/fragment/epilogue layout.
// Added: per-thread iperm A-row gather (4 offsets, resolved once, static
// unroll); 128-granular compaction (work x0.63); XCD band map (rt=(o&7)+8j
// -> A-slabs L2-shared by 16 resident blocks, B by 2). FI tiles: 2 segments;
// pass tiles: 1. Pad rows clamp to row 0; epilogue skips iperm<0.
__global__ __launch_bounds__(256, 2) void k_gemm8(
    const u16* __restrict__ xb, const u16* __restrict__ hb,
    const u16* __restrict__ Wih, const u16* __restrict__ WhhT,
    const u16* __restrict__ WinvT, const int* __restrict__ iperm,
    const int* __restrict__ flags, const int* __restrict__ meta,
    const float* __restrict__ h, float* __restrict__ out) {
  __shared__ char smem[(128 + 128) * BK * 2];  // 32 KB
  char* sA = smem;
  char* sB = smem + 128 * BK * 2;

  int nrt = meta[0];
  int tilesFI = meta[1];
  int tilesF = meta[3] >> 7;

  int o = blockIdx.x;
  int b = o & 7;                         // XCD band (round-robin dispatch)
  int q = o >> 3;
  int rt = b + 8 * (q >> 4);             // rts interleaved mod 8 per XCD
  int bcol = (q & 15) * 128;
  int brow = rt * 128;
  if (rt >= nrt) return;
  const int nseg = (rt < tilesFI) ? 2 : 1;
  const u16* Bh = (rt < tilesF) ? WhhT : WinvT;

  int t = threadIdx.x;
  int lane = t & 63;
  int wave = t >> 6;
  int wrow = (wave >> 1) * 64;
  int wcol = (wave & 1) * 64;

  f32x4 acc[4][4] = {};

  // fragment LDS byte offsets (XOR swizzle: byte ^= (row&7)<<4) -- R2 proven
  int aOff[4][2], bOff[4][2];
#pragma unroll
  for (int m = 0; m < 4; ++m)
#pragma unroll
    for (int kk = 0; kk < 2; ++kk) {
      int ar = wrow + m * 16 + (lane & 15);
      aOff[m][kk] = ar * (BK * 2) + ((kk * 64 + (lane >> 4) * 16) ^ ((ar & 7) << 4));
      int br = wcol + m * 16 + (lane & 15);
      bOff[m][kk] = br * (BK * 2) + ((kk * 64 + (lane >> 4) * 16) ^ ((br & 7) << 4));
    }

  // staging geometry (R2): lane -> row lane>>3, chunk lane&7, pre-swz source
  int srow = lane >> 3;
  int schunk = lane & 7;
  int sxor = (schunk * 16) ^ (srow << 4);

  // per-job gather: 4 A-row offsets via iperm (pad -> row 0), 4 B-row offsets
  size_t aoffs[4], boffs[4];
#pragma unroll
  for (int i = 0; i < 4; ++i) {
    int r = iperm[brow + i * 32 + wave * 8 + srow];
    if (r < 0) r = 0;
    aoffs[i] = (size_t)r * (DIM * 2) + sxor;
    boffs[i] = (size_t)(bcol + i * 32 + wave * 8 + srow) * (DIM * 2) + sxor;
  }

#pragma unroll 1
  for (int seg = 0; seg < nseg; ++seg) {
    const char* Abase = (const char*)(seg ? hb : xb);
    const char* Bbase = (const char*)(seg ? Bh : Wih);

#pragma unroll 1
    for (int k0 = 0; k0 < DIM; k0 += BK) {
      __syncthreads();
#pragma unroll
      for (int i = 0; i < 4; ++i) {
        int rbase = i * 32 + wave * 8;
        gload16(Abase + aoffs[i] + (size_t)(k0 * 2), sA + rbase * (BK * 2));
        gload16(Bbase + boffs[i] + (size_t)(k0 * 2), sB + rbase * (BK * 2));
      }
      __syncthreads();
      bf16x8 aF[4][2], bF[4][2];
#pragma unroll
      for (int m = 0; m < 4; ++m)
#pragma unroll
        for (int kk = 0; kk < 2; ++kk) {
          aF[m][kk] = *(const bf16x8*)(sA + aOff[m][kk]);
          bF[m][kk] = *(const bf16x8*)(sB + bOff[m][kk]);
        }
#pragma unroll
      for (int kk = 0; kk < 2; ++kk)
#pragma unroll
        for (int m = 0; m < 4; ++m)
#pragma unroll
          for (int n = 0; n < 4; ++n)
            acc[m][n] = __builtin_amdgcn_mfma_f32_16x16x32_bf16(
                aF[m][kk], bF[n][kk], acc[m][n], 0, 0, 0);
    }
  }

  // epilogue: scatter rows via iperm; add h for flag==2 (pass) rows
#pragma unroll
  for (int m = 0; m < 4; ++m) {
    int pbase = brow + wrow + m * 16 + (lane >> 4) * 4;
#pragma unroll
    for (int j = 0; j < 4; ++j) {
      int p = pbase + j;
      int orig = iperm[p];
      if (orig >= 0) {
        bool pass = (flags[orig] == 2);
#pragma unroll
        for (int n = 0; n < 4; ++n) {
          int col = bcol + wcol + n * 16 + (lane & 15);
          float v = acc[m][n][j];
          if (pass) v += h[(size_t)orig * DIM + col];
          out[(size_t)orig * DIM + col] = v;
        }
      }
    }
  }
}

// ---- fallback (ws too small): reg-staged 3-segment masked GEMM --------------
#define BM 128
#define BN 128
__global__ __launch_bounds__(256, 2) void k_gemm_fb(
    const float* __restrict__ x, const float* __restrict__ h,
    const u16* __restrict__ Wih, const u16* __restrict__ WhhT,
    const u16* __restrict__ WinvT, const int* __restrict__ flags,
    float* __restrict__ out) {
  __shared__ char smem[(BM + BN) * BK * 2];
  char* sA = smem;
  char* sB = smem + BM * BK * 2;

  int o = blockIdx.x;
  int swz = (o & 7) * ((int)gridDim.x >> 3) + (o >> 3);
  int brow = (swz >> 4) * BM;
  int bcol = (swz & 15) * BN;

  int t = threadIdx.x;
  int lane = t & 63;
  int wave = t >> 6;
  int wrow = (wave >> 1) * 64;
  int wcol = (wave & 1) * 64;

  f32x4 acc[4][4] = {};
  int sc = t & 15;
  int sr0 = t >> 4;

  int aOff[4][2], bOff[4][2];
#pragma unroll
  for (int m = 0; m < 4; ++m)
#pragma unroll
    for (int kk = 0; kk < 2; ++kk) {
      int ar = wrow + m * 16 + (lane & 15);
      aOff[m][kk] = ar * (BK * 2) + ((kk * 64 + (lane >> 4) * 16) ^ ((ar & 7) << 4));
      int br = wcol + m * 16 + (lane & 15);
      bOff[m][kk] = br * (BK * 2) + ((kk * 64 + (lane >> 4) * 16) ^ ((br & 7) << 4));
    }

#pragma unroll 1
  for (int seg = 0; seg < 3; ++seg) {
    const float* Asrc = (seg == 0) ? x : h;
    const u16* Bsrc = (seg == 0) ? Wih : (seg == 1) ? WhhT : WinvT;
    int want = seg - 1;

    float rmask[8];
#pragma unroll
    for (int i = 0; i < 8; ++i) {
      int r = sr0 + 16 * i;
      rmask[i] = (want < 0 || flags[brow + r] == want) ? 1.f : 0.f;
    }

#pragma unroll 1
    for (int k0 = 0; k0 < DIM; k0 += BK) {
      __syncthreads();
#pragma unroll
      for (int i = 0; i < 8; ++i) {
        int r = sr0 + 16 * i;
        f32x4 v = *(const f32x4*)(Asrc + (size_t)(brow + r) * DIM + k0 + sc * 4);
        float msk = rmask[i];
        int off = r * (BK * 2) + ((sc * 8) ^ ((r & 7) << 4));
        *(uint2*)(sA + off) =
            uint2{pack_bf2(v.x * msk, v.y * msk), pack_bf2(v.z * msk, v.w * msk)};
      }
#pragma unroll
      for (int i = 0; i < 4; ++i) {
        int ch = t + 256 * i;
        int r = ch >> 3;
        int c = ch & 7;
        uint4 v = *(const uint4*)(Bsrc + (size_t)(bcol + r) * DIM + k0 + c * 8);
        int off = r * (BK * 2) + ((c * 16) ^ ((r & 7) << 4));
        *(uint4*)(sB + off) = v;
      }
      __syncthreads();
      bf16x8 aF2[4][2], bF2[4][2];
#pragma unroll
      for (int m = 0; m < 4; ++m)
#pragma unroll
        for (int kk = 0; kk < 2; ++kk) {
          aF2[m][kk] = *(const bf16x8*)(sA + aOff[m][kk]);
          bF2[m][kk] = *(const bf16x8*)(sB + bOff[m][kk]);
        }
#pragma unroll
      for (int kk = 0; kk < 2; ++kk)
#pragma unroll
        for (int m = 0; m < 4; ++m)
#pragma unroll
          for (int n = 0; n < 4; ++n)
            acc[m][n] = __builtin_amdgcn_mfma_f32_16x16x32_bf16(
                aF2[m][kk], bF2[n][kk], acc[m][n], 0, 0, 0);
    }
  }

#pragma unroll
  for (int m = 0; m < 4; ++m) {
    int rbase = brow + wrow + m * 16 + (lane >> 4) * 4;
#pragma unroll
    for (int j = 0; j < 4; ++j) {
      int row = rbase + j;
      bool pass = (flags[row] == 2);
#pragma unroll
      for (int n = 0; n < 4; ++n) {
        int col = bcol + wcol + n * 16 + (lane & 15);
        float v = acc[m][n][j];
        if (pass) v += h[(size_t)row * DIM + col];
        out[(size_t)row * DIM + col] = v;
      }
    }
  }
}

extern "C" void kernel_launch(void* const* d_in, const int* in_sizes, int n_in,
                              void* d_out, int out_size, void* d_ws, size_t ws_size,
                              hipStream_t stream) {
  const float* x = (const float*)d_in[0];
  const float* h = (const float*)d_in[1];
  const float* W_ih = (const float*)d_in[2];
  const float* W_hh = (const float*)d_in[3];
  const float* W_inv = (const float*)d_in[4];
  float* out = (float*)d_out;

  char* ws = (char*)d_ws;
  int* flags = (int*)ws;                                  // 64 KB
  int* meta = (int*)(ws + 65536);                         // 256 B
  int* iperm = (int*)(ws + 65536 + 256);                  // 66 KB
  u16* WihB = (u16*)(ws + 139264);                        // 8 MB
  u16* WhhT = WihB + (size_t)DIM * DIM;                   // 8 MB
  u16* WinvT = WhhT + (size_t)DIM * DIM;                  // 8 MB
  u16* xb = WinvT + (size_t)DIM * DIM;                    // 64 MB
  u16* hb = xb + (size_t)B_ROWS * DIM;                    // 64 MB
  size_t need = 139264 + 3ull * DIM * DIM * 2 + 2ull * B_ROWS * DIM * 2;

  k_convert<<<(DIM * DIM / 4) / 256, 256, 0, stream>>>(W_ih, WihB);
  k_transpose<<<dim3(DIM / 32, DIM / 32), 256, 0, stream>>>(W_hh, WhhT);
  k_transpose<<<dim3(DIM / 32, DIM / 32), 256, 0, stream>>>(W_inv, WinvT);

  if (ws_size >= need) {
    k_prep2<<<B_ROWS / 4, 256, 0, stream>>>(x, h, W_ih, flags, xb, hb);
    k_scan<<<1, 256, 0, stream>>>(flags, iperm, meta);
    // grid: 8 XCD bands x 17 rt-slots x 16 cols (rt>=nrt blocks return)
    k_gemm8<<<8 * 17 * 16, 256, 0, stream>>>(xb, hb, WihB, WhhT, WinvT, iperm,
                                             flags, meta, h, out);
  } else {
    k_prep2<<<B_ROWS / 4, 256, 0, stream>>>(x, h, W_ih, flags,
                                            (u16*)(ws + 139264),
                                            (u16*)(ws + 139264));
    k_gemm_fb<<<(B_ROWS / BM) * (DIM / BN), 256, 0, stream>>>(x, h, WihB, WhhT,
                                                              WinvT, flags, out);
  }
}